// Round 10
// baseline (844.882 us; speedup 1.0000x reference)
//
#include <hip/hip_runtime.h>
#include <hip/hip_fp16.h>

// ---------------------------------------------------------------------------
// GCN 6-layer forward on MI355X — fused aggregate-then-transform layers.
//   Identity: A_hat(H W) = (A_hat H) W. Per layer, ONE kernel:
//     per wave: gather-sum 16 nodes' prescaled rows hp=inv*h (fp32 acc)
//               -> LDS ms[16][128] -> MFMA vs register-resident Wt
//               -> store inv*relu(inv*t + b) (prescale for next layer).
//   No hs intermediate, no gemm dispatch, no global sync per layer.
//   State fp16 (fp8 failed R8: absmax 1.9e-3 > thr 3.9e-5).
// ---------------------------------------------------------------------------

static inline int ceil_div(int a, int b) { return (a + b - 1) / b; }

typedef _Float16 f16x8 __attribute__((ext_vector_type(8)));
typedef _Float16 f16x4 __attribute__((ext_vector_type(4)));
typedef _Float16 f16x2 __attribute__((ext_vector_type(2)));
typedef float f32x4 __attribute__((ext_vector_type(4)));

// ---------------- setup kernels ----------------

__global__ __launch_bounds__(256) void hist_i32(const int* __restrict__ idx,
                                                int* __restrict__ cnt, int n) {
  int i = blockIdx.x * 256 + threadIdx.x;
  if (i < n) atomicAdd(&cnt[idx[i]], 1);
}

// inclusive scan chunk + inv = rsqrt(deg+1) folded in
__global__ __launch_bounds__(256) void scanA(const int* __restrict__ deg,
                                             int* __restrict__ tmp,
                                             int* __restrict__ sums,
                                             float* __restrict__ inv, int n) {
  __shared__ int s[256];
  int t = threadIdx.x;
  int gid = blockIdx.x * 256 + t;
  int d = (gid < n) ? deg[gid] : 0;
  if (gid < n) inv[gid] = rsqrtf((float)(d + 1));  // +1 = self loop
  s[t] = d;
  __syncthreads();
  for (int off = 1; off < 256; off <<= 1) {
    int add = (t >= off) ? s[t - off] : 0;
    __syncthreads();
    s[t] += add;
    __syncthreads();
  }
  if (gid < n) tmp[gid] = s[t];
  if (t == 255) sums[blockIdx.x] = s[255];
}

__global__ __launch_bounds__(256) void scanB(int* __restrict__ sums, int nchunk) {
  __shared__ int s[256];
  int t = threadIdx.x;
  s[t] = (t < nchunk) ? sums[t] : 0;
  __syncthreads();
  for (int off = 1; off < 256; off <<= 1) {
    int add = (t >= off) ? s[t - off] : 0;
    __syncthreads();
    s[t] += add;
    __syncthreads();
  }
  if (t < nchunk) sums[t] = s[t];
}

// rp[gid+1] = global inclusive; cursor[gid] = rp[gid] (exclusive) folded in
__global__ __launch_bounds__(256) void scanC(const int* __restrict__ tmp,
                                             const int* __restrict__ sums,
                                             const int* __restrict__ deg,
                                             int* __restrict__ rp,
                                             int* __restrict__ cursor, int n) {
  int gid = blockIdx.x * 256 + threadIdx.x;
  if (gid < n) {
    int off = (blockIdx.x > 0) ? sums[blockIdx.x - 1] : 0;
    int incl = tmp[gid] + off;
    rp[gid + 1] = incl;
    cursor[gid] = incl - deg[gid];
    if (gid == 0) rp[0] = 0;
  }
}

__global__ __launch_bounds__(256) void scatter_edges(const int* __restrict__ src,
                                                     const int* __restrict__ dst,
                                                     int* __restrict__ cursor,
                                                     int* __restrict__ col, int E) {
  int i = blockIdx.x * 256 + threadIdx.x;
  if (i < E) {
    int d = dst[i];
    int pos = atomicAdd(&cursor[d], 1);
    col[pos] = src[i];
  }
}

// fused: [0,nbF) hp=fp16(inv*x) | [nbF,nbF+384) W->Wt fp16 | rest: batch bsearch
struct WP { const float* p[6]; };
__global__ __launch_bounds__(256) void setup_fuse(const float* __restrict__ x,
                                                  const float* __restrict__ inv,
                                                  _Float16* __restrict__ hp,
                                                  WP wp, _Float16* __restrict__ wt,
                                                  const int* __restrict__ batch,
                                                  int* __restrict__ gstart,
                                                  int nelem, int nodes, int B,
                                                  int nbF) {
  int blk = blockIdx.x;
  if (blk < nbF) {
    int i = (blk * 256 + threadIdx.x) * 4;
    if (i < nelem) {
      float iv = inv[i >> 7];
      float4 v = *(const float4*)&x[i];
      f16x4 o = {(_Float16)(v.x * iv), (_Float16)(v.y * iv),
                 (_Float16)(v.z * iv), (_Float16)(v.w * iv)};
      *(f16x4*)&hp[i] = o;
    }
  } else if (blk < nbF + 384) {
    int b2 = blk - nbF;
    int wi = b2 >> 6;                            // 64 blocks per weight
    int e = (b2 & 63) * 256 + threadIdx.x;       // 0..16383
    int k = e >> 7, c = e & 127;
    wt[((size_t)wi << 14) + (size_t)c * 128 + k] = (_Float16)wp.p[wi][e];
  } else {
    int g = (blk - nbF - 384) * 256 + threadIdx.x;
    if (g <= B) {
      int lo = 0, hi = nodes;
      while (lo < hi) {
        int mid = (lo + hi) >> 1;
        if (batch[mid] < g) lo = mid + 1; else hi = mid;
      }
      gstart[g] = lo;
    }
  }
}

// ---------------- fused layer kernel ----------------

// For each group of 16 nodes (one wave):
//  1) gather: m_j = sum_e hp[col[e]] + hp[node_j]  (fp32, lane covers 2 cols)
//     -> ms[wv][j][128] in LDS (per-wave region, no block barrier needed)
//  2) A-frags from ms (B-operand mapping: lane -> node j=l&15, k=(l>>4)*8),
//     MFMA vs register Wt frags (R7-verified swapped mapping):
//     D: lane -> node = base+(l&15), cols = ct*16+(l>>4)*4+[0..4)
//  3) t = m@W; h' = inv*t + bias; store dorelu ? inv*relu(h') : h'
__global__ __launch_bounds__(256, 2) void layer_fused(
    const _Float16* __restrict__ hp, const _Float16* __restrict__ Wt,
    const float* __restrict__ inv, const int* __restrict__ col,
    const int* __restrict__ rp, const float* __restrict__ bias,
    _Float16* __restrict__ out, int n, int dorelu) {
  __shared__ float ms[4][16][132];
  int lane = threadIdx.x & 63;
  int wv = threadIdx.x >> 6;  // 0..3
  int r = lane & 15, g = lane >> 4;

  // ---- load all Wt fragments once (static indices -> registers) ----
  f16x8 b[8][4];
  const _Float16* bp = Wt + (size_t)r * 128 + g * 8;
#pragma unroll
  for (int ct = 0; ct < 8; ++ct) {
#pragma unroll
    for (int ks = 0; ks < 4; ++ks)
      b[ct][ks] = *(const f16x8*)(bp + ct * 2048 + ks * 32);
  }

  const f16x2* hp2 = (const f16x2*)hp;
  int ngroups = (n + 15) >> 4;
  int nwaves = (int)gridDim.x * 4;

  for (int grp = blockIdx.x * 4 + wv; grp < ngroups; grp += nwaves) {
    int base = grp << 4;

    // ---- phase 1: gather 16 nodes into ms[wv] ----
    for (int j = 0; j < 16; ++j) {
      int node = base + j;
      float ax = 0.f, ay = 0.f, bx = 0.f, by = 0.f;
      float cx = 0.f, cy = 0.f, dx = 0.f, dy = 0.f;
      if (node < n) {
        int beg = rp[node], end = rp[node + 1];
        f16x2 sv = hp2[(size_t)node * 64 + lane];  // self (already prescaled)
        ax = (float)sv[0]; ay = (float)sv[1];
        int e = beg;
        for (; e + 4 <= end; e += 4) {
          int i0 = col[e + 0], i1 = col[e + 1], i2 = col[e + 2], i3 = col[e + 3];
          f16x2 v0 = hp2[(size_t)i0 * 64 + lane];
          f16x2 v1 = hp2[(size_t)i1 * 64 + lane];
          f16x2 v2 = hp2[(size_t)i2 * 64 + lane];
          f16x2 v3 = hp2[(size_t)i3 * 64 + lane];
          ax += (float)v0[0]; ay += (float)v0[1];
          bx += (float)v1[0]; by += (float)v1[1];
          cx += (float)v2[0]; cy += (float)v2[1];
          dx += (float)v3[0]; dy += (float)v3[1];
        }
        for (; e < end; ++e) {
          f16x2 v = hp2[(size_t)col[e] * 64 + lane];
          ax += (float)v[0]; ay += (float)v[1];
        }
      }
      *(float2*)&ms[wv][j][2 * lane] =
          make_float2((ax + bx) + (cx + dx), (ay + by) + (cy + dy));
    }

    // ---- phase 2: MFMA (A-frags from ms; per-wave LDS, in-wave dep only) ----
    f32x4 acc[8];
#pragma unroll
    for (int ct = 0; ct < 8; ++ct) acc[ct] = (f32x4){0.f, 0.f, 0.f, 0.f};

#pragma unroll
    for (int ks = 0; ks < 4; ++ks) {
      const float* mrow = &ms[wv][r][ks * 32 + g * 8];
      f16x8 a;
#pragma unroll
      for (int kk = 0; kk < 8; ++kk) a[kk] = (_Float16)mrow[kk];
#pragma unroll
      for (int ct = 0; ct < 8; ++ct)
        acc[ct] = __builtin_amdgcn_mfma_f32_16x16x32_f16(b[ct][ks], a, acc[ct], 0, 0, 0);
    }

    // ---- phase 3: epilogue. lane owns node base+r, cols ct*16+g*4+[0..4) ----
    int node = base + r;
    if (node < n) {
      float iv = inv[node];
      _Float16* op = out + (size_t)node * 128 + g * 4;
#pragma unroll
      for (int ct = 0; ct < 8; ++ct) {
        const float4 bb = *(const float4*)&bias[ct * 16 + g * 4];
        float r0 = iv * acc[ct][0] + bb.x;
        float r1 = iv * acc[ct][1] + bb.y;
        float r2 = iv * acc[ct][2] + bb.z;
        float r3 = iv * acc[ct][3] + bb.w;
        if (dorelu) {  // store prescaled for next layer: inv * relu(h')
          r0 = iv * fmaxf(r0, 0.f); r1 = iv * fmaxf(r1, 0.f);
          r2 = iv * fmaxf(r2, 0.f); r3 = iv * fmaxf(r3, 0.f);
        }
        __half2 lo = __floats2half2_rn(r0, r1);
        __half2 hi = __floats2half2_rn(r2, r3);
        uint2 sv;
        sv.x = *(unsigned*)&lo;
        sv.y = *(unsigned*)&hi;
        *(uint2*)(op + ct * 16) = sv;
      }
    }
  }
}

// segment-mean pool: one block (128 threads) per graph, fp16 in, fp32 acc
__global__ __launch_bounds__(128) void pool_mean(const __half* __restrict__ h,
                                                 const int* __restrict__ gstart,
                                                 float* __restrict__ pooled) {
  int g = blockIdx.x;
  int c = threadIdx.x;
  int s = gstart[g], e = gstart[g + 1];
  float acc = 0.f;
  for (int v = s; v < e; ++v) acc += __half2float(h[(size_t)v * 128 + c]);
  int cnt = e - s;
  pooled[(size_t)g * 128 + c] = acc / (float)(cnt > 0 ? cnt : 1);
}

// out[g][c] = sum_k pooled[g][k] * lin_W[k][c] + lin_b[c]   (512x32 outputs)
__global__ __launch_bounds__(256) void final_lin(const float* __restrict__ pooled,
                                                 const float* __restrict__ lw,
                                                 const float* __restrict__ lb,
                                                 float* __restrict__ out, int total) {
  int idx = blockIdx.x * 256 + threadIdx.x;
  if (idx >= total) return;
  int g = idx >> 5;
  int c = idx & 31;
  float s = 0.f;
#pragma unroll 8
  for (int k = 0; k < 128; ++k) s += pooled[(size_t)g * 128 + k] * lw[k * 32 + c];
  out[idx] = s + lb[c];
}

// ---------------- launch ----------------

extern "C" void kernel_launch(void* const* d_in, const int* in_sizes, int n_in,
                              void* d_out, int out_size, void* d_ws, size_t ws_size,
                              hipStream_t stream) {
  const float* x = (const float*)d_in[0];
  const int* ei = (const int*)d_in[1];
  const int* batch = (const int*)d_in[2];
  WP wp;
  const float* bvec[6];
  for (int i = 0; i < 6; ++i) {
    wp.p[i] = (const float*)d_in[3 + 2 * i];
    bvec[i] = (const float*)d_in[4 + 2 * i];
  }
  const float* linW = (const float*)d_in[15];
  const float* linb = (const float*)d_in[16];
  float* out = (float*)d_out;

  const int F = 128, H = 128, C = 32;
  const int N = in_sizes[0] / F;
  const int E = in_sizes[1] / 2;
  const int B = out_size / C;  // 512
  const int* src = ei;
  const int* dst = ei + E;

  // workspace carve-out (256B aligned slices)
  char* w = (char*)d_ws;
  auto alloc = [&](size_t bytes) -> char* {
    char* p = w;
    w += (bytes + 255) & ~(size_t)255;
    return p;
  };
  int* deg = (int*)alloc((size_t)N * 4);
  float* inv = (float*)alloc((size_t)N * 4);
  int* tmp = (int*)alloc((size_t)N * 4);
  int* sums = (int*)alloc(256 * 4);
  int* rp = (int*)alloc((size_t)(N + 1) * 4);
  int* cursor = (int*)alloc((size_t)N * 4);
  int* col = (int*)alloc((size_t)E * 4);
  int* gstart = (int*)alloc((size_t)(B + 1) * 4);
  _Float16* h16a = (_Float16*)alloc((size_t)N * H * 2);
  _Float16* h16b = (_Float16*)alloc((size_t)N * H * 2);
  _Float16* wt16 = (_Float16*)alloc((size_t)6 * H * H * 2);
  float* pooled = (float*)alloc((size_t)B * H * 4);
  (void)n_in; (void)ws_size;

  hipMemsetAsync(deg, 0, (size_t)N * 4, stream);

  hist_i32<<<ceil_div(E, 256), 256, 0, stream>>>(dst, deg, E);

  int nchunk = ceil_div(N, 256);  // 196 for N=50000, fits scanB's 256 slots
  scanA<<<nchunk, 256, 0, stream>>>(deg, tmp, sums, inv, N);
  scanB<<<1, 256, 0, stream>>>(sums, nchunk);
  scanC<<<nchunk, 256, 0, stream>>>(tmp, sums, deg, rp, cursor, N);

  int nbF = ceil_div(N * F / 4, 256);
  int nbBS = ceil_div(B + 1, 256);
  setup_fuse<<<nbF + 384 + nbBS, 256, 0, stream>>>(x, inv, h16a, wp, wt16, batch,
                                                   gstart, N * F, N, B, nbF);

  scatter_edges<<<ceil_div(E, 256), 256, 0, stream>>>(src, dst, cursor, col, E);

  // ping-pong: a->b, b->a, ... ; after 6 layers result is in h16a
  _Float16* cur = h16a;
  _Float16* nxt = h16b;
  for (int l = 0; l < 6; ++l) {
    layer_fused<<<512, 256, 0, stream>>>(cur, wt16 + ((size_t)l << 14), inv, col, rp,
                                         bvec[l], nxt, N, (l < 5) ? 1 : 0);
    _Float16* t = cur; cur = nxt; nxt = t;
  }

  pool_mean<<<B, 128, 0, stream>>>((const __half*)cur, gstart, pooled);
  final_lin<<<ceil_div(B * C, 256), 256, 0, stream>>>(pooled, linW, linb, out, B * C);
}